// Round 1
// baseline (260.034 us; speedup 1.0000x reference)
//
#include <hip/hip_runtime.h>
#include <hip/hip_bf16.h>

// Problem constants
#define B_ROWS 32768
#define K1 320      // meas_in = 256 + 64
#define N1 512      // 4 branches * 128
#define K2 544      // 512 (H') + 16 (ut_dt) + 1 (ones->czn) + 15 pad
#define N2 256      // D
#define LN_EPS 1e-5f

typedef __bf16 bf16;
using bf16x8 = __attribute__((ext_vector_type(8))) __bf16;
using f32x4  = __attribute__((ext_vector_type(4))) float;

// ---------------- workspace layout (bytes) ----------------
// Xbf   [B,320] bf16 : 20,971,520   @ 0
// Hext  [B,544] bf16 : 35,651,584   @ 20971520
// W1eff [512,320]bf16:    327,680   @ 56623104
// Pext  [256,544]bf16:    278,528   @ 56950784
// Mtmp  [4,64,128]f32:    131,072   @ 57229312
// cvec  [256]    f32 :      1,024   @ 57360384
// total ~57.4 MB

__device__ __forceinline__ void gld_lds16(const bf16* g, bf16* l) {
  __builtin_amdgcn_global_load_lds((const __attribute__((address_space(1))) void*)g,
                                   (__attribute__((address_space(3))) void*)l,
                                   16, 0, 0);
}

// ---------------- prep 1: W1eff (gate-folded), Mtmp = BmatG*W2, cvec = BmatG*b2
__global__ __launch_bounds__(256) void prep_weights1(
    const float* __restrict__ gates, const float* __restrict__ W1,
    const float* __restrict__ Bmat,  const float* __restrict__ W2,
    const float* __restrict__ b2,
    bf16* __restrict__ W1eff, float* __restrict__ Mtmp, float* __restrict__ cvec)
{
  const int stride = gridDim.x * blockDim.x;
  const int id = blockIdx.x * blockDim.x + threadIdx.x;
  // W1eff: [512,320] ; flat identical to W1 flat layout
  for (int i = id; i < 512 * 320; i += stride) {
    int col = i / 320;            // n*128+h
    int k   = i - col * 320;
    float wv = W1[i];
    if (k < 256) {
      float g = gates[(col >> 7) * 256 + k];
      wv *= 1.f / (1.f + expf(-g));
    }
    W1eff[i] = (bf16)wv;
  }
  // Mtmp[n,r,h] = sum_j Bmat[n,r,j]*W2[n,j,h], j<64
  for (int i = id; i < 4 * 64 * 128; i += stride) {
    int n = i >> 13, r = (i >> 7) & 63, h = i & 127;
    float s = 0.f;
    for (int j = 0; j < 64; ++j)
      s += Bmat[(n * 64 + r) * 80 + j] * W2[(n * 64 + j) * 128 + h];
    Mtmp[i] = s;
  }
  // cvec[n*64+r] = sum_j BmatG[n,r,j]*b2[n,j]
  for (int i = id; i < 256; i += stride) {
    int n = i >> 6, r = i & 63;
    float s = 0.f;
    for (int j = 0; j < 64; ++j)
      s += Bmat[(n * 64 + r) * 80 + j] * b2[n * 64 + j];
    cvec[i] = s;
  }
}

// ---------------- prep 2: Pext [256,544] = [P | Q | czn | 0]
__global__ __launch_bounds__(256) void prep_weights2(
    const float* __restrict__ Wout, const float* __restrict__ Bmat,
    const float* __restrict__ Mtmp, const float* __restrict__ cvec,
    bf16* __restrict__ Pext)
{
  const int stride = gridDim.x * blockDim.x;
  const int id = blockIdx.x * blockDim.x + threadIdx.x;
  for (int i = id; i < 256 * 544; i += stride) {
    int d = i / 544;
    int c = i - d * 544;
    float s = 0.f;
    if (c < 512) {
      int n = c >> 7, h = c & 127;
      for (int r = 0; r < 64; ++r)
        s += Wout[(n * 256 + d) * 64 + r] * Mtmp[(n * 64 + r) * 128 + h];
    } else if (c < 528) {
      int u = c - 512;
      for (int n = 0; n < 4; ++n)
        for (int r = 0; r < 64; ++r)
          s += Wout[(n * 256 + d) * 64 + r] * Bmat[(n * 64 + r) * 80 + 64 + u];
    } else if (c == 528) {
      for (int n = 0; n < 4; ++n)
        for (int r = 0; r < 64; ++r)
          s += Wout[(n * 256 + d) * 64 + r] * cvec[n * 64 + r];
    }
    Pext[i] = (bf16)s;
  }
}

// ---------------- input conversion: Xbf = [z_dyn | z_static] bf16; Hext tail cols
__global__ __launch_bounds__(256) void prep_inputs(
    const float* __restrict__ zdyn, const float* __restrict__ zst,
    const float* __restrict__ ut,   const float* __restrict__ dtp,
    bf16* __restrict__ Xbf, bf16* __restrict__ Hext)
{
  const int stride = gridDim.x * blockDim.x;
  const int id = blockIdx.x * blockDim.x + threadIdx.x;
  const float dtv = dtp[0];
  for (int i = id; i < B_ROWS * 64; i += stride) {
    int b = i >> 6, c4 = (i & 63) << 2;
    float4 v = *(const float4*)&zdyn[(size_t)b * 256 + c4];
    bf16* o = &Xbf[(size_t)b * 320 + c4];
    o[0] = (bf16)v.x; o[1] = (bf16)v.y; o[2] = (bf16)v.z; o[3] = (bf16)v.w;
  }
  for (int i = id; i < B_ROWS * 16; i += stride) {
    int b = i >> 4, c4 = (i & 15) << 2;
    float4 v = *(const float4*)&zst[(size_t)b * 64 + c4];
    bf16* o = &Xbf[(size_t)b * 320 + 256 + c4];
    o[0] = (bf16)v.x; o[1] = (bf16)v.y; o[2] = (bf16)v.z; o[3] = (bf16)v.w;
  }
  for (int i = id; i < B_ROWS * 32; i += stride) {
    int b = i >> 5, c = i & 31;
    float v = (c < 16) ? ut[(size_t)b * 16 + c] * dtv : ((c == 16) ? 1.f : 0.f);
    Hext[(size_t)b * 544 + 512 + c] = (bf16)v;
  }
}

// ---------------- GEMM1: H' = GELU(LN(X*W1eff^T + b1)) -> Hext[:, :512] bf16
// 128x128 tile, BK=32, 4 waves (each 64x64 via 4x4 of 16x16x32 MFMA)
__global__ __launch_bounds__(256) void gemm1_ln_gelu(
    const bf16* __restrict__ X, const bf16* __restrict__ W,
    const float* __restrict__ b1, const float* __restrict__ gamma,
    const float* __restrict__ beta, bf16* __restrict__ H)
{
  constexpr int K = K1, NT = K1 / 32;
  __shared__ __align__(16) bf16 As[128 * 32];
  __shared__ __align__(16) bf16 Bs[128 * 32];
  __shared__ bf16 hs[128 * 130];   // padded stride 130 -> LN stat reads conflict-free
  __shared__ float smu[128], srs[128];

  const int t = threadIdx.x;
  const int lane = t & 63, w = t >> 6;
  const int rowBase = blockIdx.x * 128;
  const int colBase = blockIdx.y * 128;

  // staging: slot s holds 16B chunk (row=s>>2, qk = (s&3) ^ ((row>>1)&3))
  const int s0 = t, s1 = t + 256;
  const int r0 = s0 >> 2, r1 = s1 >> 2;
  const int q0 = (s0 & 3) ^ ((r0 >> 1) & 3);
  const int q1 = (s1 & 3) ^ ((r1 >> 1) & 3);
  const bf16* gA0 = X + (size_t)(rowBase + r0) * K + q0 * 8;
  const bf16* gA1 = X + (size_t)(rowBase + r1) * K + q1 * 8;
  const bf16* gB0 = W + (size_t)(colBase + r0) * K + q0 * 8;
  const bf16* gB1 = W + (size_t)(colBase + r1) * K + q1 * 8;
  bf16* lA0 = As + w * 512;
  bf16* lA1 = As + 2048 + w * 512;
  bf16* lB0 = Bs + w * 512;
  bf16* lB1 = Bs + 2048 + w * 512;

  f32x4 acc[4][4];
  #pragma unroll
  for (int i = 0; i < 4; ++i)
    #pragma unroll
    for (int j = 0; j < 4; ++j)
      #pragma unroll
      for (int r = 0; r < 4; ++r) acc[i][j][r] = 0.f;

  const int m16 = lane & 15, q = lane >> 4;
  const int wr = (w >> 1) * 64, wc = (w & 1) * 64;

  for (int it = 0; it < NT; ++it) {
    const int ko = it * 32;
    gld_lds16(gA0 + ko, lA0);
    gld_lds16(gA1 + ko, lA1);
    gld_lds16(gB0 + ko, lB0);
    gld_lds16(gB1 + ko, lB1);
    asm volatile("s_waitcnt vmcnt(0)" ::: "memory");
    __syncthreads();
    bf16x8 af[4], bfr[4];
    #pragma unroll
    for (int i = 0; i < 4; ++i) {
      int r = wr + i * 16 + m16;
      af[i]  = *(const bf16x8*)&As[r * 32 + ((q ^ ((r >> 1) & 3)) * 8)];
      int c = wc + i * 16 + m16;
      bfr[i] = *(const bf16x8*)&Bs[c * 32 + ((q ^ ((c >> 1) & 3)) * 8)];
    }
    #pragma unroll
    for (int i = 0; i < 4; ++i)
      #pragma unroll
      for (int j = 0; j < 4; ++j)
        acc[i][j] = __builtin_amdgcn_mfma_f32_16x16x32_bf16(af[i], bfr[j], acc[i][j], 0, 0, 0);
    __syncthreads();
  }

  // epilogue: +b1 -> hs (bf16), LN stats, gamma/beta, exact GELU, store
  #pragma unroll
  for (int i = 0; i < 4; ++i) {
    #pragma unroll
    for (int j = 0; j < 4; ++j) {
      int col = wc + j * 16 + m16;
      float bb = b1[colBase + col];
      #pragma unroll
      for (int r = 0; r < 4; ++r) {
        int row = wr + i * 16 + q * 4 + r;
        hs[row * 130 + col] = (bf16)(acc[i][j][r] + bb);
      }
    }
  }
  __syncthreads();
  if (t < 128) {
    float s = 0.f, s2 = 0.f;
    for (int c = 0; c < 128; ++c) {
      float v = (float)hs[t * 130 + c];
      s += v; s2 += v * v;
    }
    float mu = s * 0.0078125f;
    float var = s2 * 0.0078125f - mu * mu;
    smu[t] = mu;
    srs[t] = rsqrtf(fmaxf(var, 0.f) + LN_EPS);
  }
  __syncthreads();
  for (int e = t; e < 128 * 128; e += 256) {
    int row = e >> 7, col = e & 127;
    float v = ((float)hs[row * 130 + col] - smu[row]) * srs[row];
    v = v * gamma[colBase + col] + beta[colBase + col];
    float gl = 0.5f * v * (1.f + erff(v * 0.70710678f));
    H[(size_t)(rowBase + row) * K2 + colBase + col] = (bf16)gl;
  }
}

// ---------------- GEMM2: Z = Hext * Pext^T  (K=544 folds ut_dt*Q^T and czn)
__global__ __launch_bounds__(256) void gemm2_z(
    const bf16* __restrict__ A, const bf16* __restrict__ Bm, float* __restrict__ Z)
{
  constexpr int K = K2, NT = K2 / 32;  // 17
  __shared__ __align__(16) bf16 As[128 * 32];
  __shared__ __align__(16) bf16 Bs[128 * 32];

  const int t = threadIdx.x;
  const int lane = t & 63, w = t >> 6;
  const int rowBase = blockIdx.x * 128;
  const int colBase = blockIdx.y * 128;

  const int s0 = t, s1 = t + 256;
  const int r0 = s0 >> 2, r1 = s1 >> 2;
  const int q0 = (s0 & 3) ^ ((r0 >> 1) & 3);
  const int q1 = (s1 & 3) ^ ((r1 >> 1) & 3);
  const bf16* gA0 = A + (size_t)(rowBase + r0) * K + q0 * 8;
  const bf16* gA1 = A + (size_t)(rowBase + r1) * K + q1 * 8;
  const bf16* gB0 = Bm + (size_t)(colBase + r0) * K + q0 * 8;
  const bf16* gB1 = Bm + (size_t)(colBase + r1) * K + q1 * 8;
  bf16* lA0 = As + w * 512;
  bf16* lA1 = As + 2048 + w * 512;
  bf16* lB0 = Bs + w * 512;
  bf16* lB1 = Bs + 2048 + w * 512;

  f32x4 acc[4][4];
  #pragma unroll
  for (int i = 0; i < 4; ++i)
    #pragma unroll
    for (int j = 0; j < 4; ++j)
      #pragma unroll
      for (int r = 0; r < 4; ++r) acc[i][j][r] = 0.f;

  const int m16 = lane & 15, q = lane >> 4;
  const int wr = (w >> 1) * 64, wc = (w & 1) * 64;

  for (int it = 0; it < NT; ++it) {
    const int ko = it * 32;
    gld_lds16(gA0 + ko, lA0);
    gld_lds16(gA1 + ko, lA1);
    gld_lds16(gB0 + ko, lB0);
    gld_lds16(gB1 + ko, lB1);
    asm volatile("s_waitcnt vmcnt(0)" ::: "memory");
    __syncthreads();
    bf16x8 af[4], bfr[4];
    #pragma unroll
    for (int i = 0; i < 4; ++i) {
      int r = wr + i * 16 + m16;
      af[i]  = *(const bf16x8*)&As[r * 32 + ((q ^ ((r >> 1) & 3)) * 8)];
      int c = wc + i * 16 + m16;
      bfr[i] = *(const bf16x8*)&Bs[c * 32 + ((q ^ ((c >> 1) & 3)) * 8)];
    }
    #pragma unroll
    for (int i = 0; i < 4; ++i)
      #pragma unroll
      for (int j = 0; j < 4; ++j)
        acc[i][j] = __builtin_amdgcn_mfma_f32_16x16x32_bf16(af[i], bfr[j], acc[i][j], 0, 0, 0);
    __syncthreads();
  }

  #pragma unroll
  for (int i = 0; i < 4; ++i) {
    #pragma unroll
    for (int j = 0; j < 4; ++j) {
      int col = colBase + wc + j * 16 + m16;
      #pragma unroll
      for (int r = 0; r < 4; ++r) {
        int row = rowBase + wr + i * 16 + q * 4 + r;
        Z[(size_t)row * 256 + col] = acc[i][j][r];
      }
    }
  }
}

// ---------------- yt = Z*C^T + ut_dt*D^T
__global__ __launch_bounds__(256) void yt_kernel(
    const float* __restrict__ Z, const float* __restrict__ Cm,
    const float* __restrict__ Dm, const float* __restrict__ ut,
    const float* __restrict__ dtp, float* __restrict__ yt)
{
  __shared__ float Zs[64 * 256];   // row-rotated to kill bank conflicts
  const int t = threadIdx.x;
  const int r0 = blockIdx.x * 64;
  for (int i = t; i < 64 * 64; i += 256) {
    int row = i >> 6, c4 = (i & 63) << 2;
    float4 v = *(const float4*)&Z[(size_t)(r0 + row) * 256 + c4];
    Zs[row * 256 + ((c4 + 0 + row) & 255)] = v.x;
    Zs[row * 256 + ((c4 + 1 + row) & 255)] = v.y;
    Zs[row * 256 + ((c4 + 2 + row) & 255)] = v.z;
    Zs[row * 256 + ((c4 + 3 + row) & 255)] = v.w;
  }
  __syncthreads();
  const int row = t & 63, grp = t >> 6;
  const int o0 = grp * 7;
  float accv[7] = {0.f, 0.f, 0.f, 0.f, 0.f, 0.f, 0.f};
  const float* crow[7];
  #pragma unroll
  for (int oo = 0; oo < 7; ++oo) {
    int o = o0 + oo; if (o > 24) o = 24;
    crow[oo] = Cm + o * 256;       // wave-uniform -> scalar loads
  }
  for (int k = 0; k < 256; ++k) {
    float z = Zs[row * 256 + ((k + row) & 255)];
    #pragma unroll
    for (int oo = 0; oo < 7; ++oo) accv[oo] += z * crow[oo][k];
  }
  const float dtv = dtp[0];
  const int gr = r0 + row;
  float utr[16];
  #pragma unroll
  for (int u = 0; u < 16; ++u) utr[u] = ut[(size_t)gr * 16 + u] * dtv;
  #pragma unroll
  for (int oo = 0; oo < 7; ++oo) {
    int o = o0 + oo;
    if (o < 25) {
      float s = accv[oo];
      #pragma unroll
      for (int u = 0; u < 16; ++u) s += utr[u] * Dm[o * 16 + u];
      yt[(size_t)gr * 25 + o] = s;
    }
  }
}

extern "C" void kernel_launch(void* const* d_in, const int* in_sizes, int n_in,
                              void* d_out, int out_size, void* d_ws, size_t ws_size,
                              hipStream_t stream) {
  const float* zdyn  = (const float*)d_in[0];
  const float* zst   = (const float*)d_in[1];
  const float* dtp   = (const float*)d_in[2];
  const float* ut    = (const float*)d_in[3];
  const float* gates = (const float*)d_in[4];
  const float* W1    = (const float*)d_in[5];
  const float* b1    = (const float*)d_in[6];
  const float* gamma = (const float*)d_in[7];
  const float* beta  = (const float*)d_in[8];
  const float* W2    = (const float*)d_in[9];
  const float* b2    = (const float*)d_in[10];
  // d_in[11], d_in[12] (lam_real/lam_imag) are dead: h0 = 0
  const float* Bmat  = (const float*)d_in[13];
  const float* Wout  = (const float*)d_in[14];
  const float* Cm    = (const float*)d_in[15];
  const float* Dm    = (const float*)d_in[16];

  char* ws = (char*)d_ws;
  bf16*  Xbf   = (bf16*)(ws);
  bf16*  Hext  = (bf16*)(ws + 20971520);
  bf16*  W1eff = (bf16*)(ws + 56623104);
  bf16*  Pext  = (bf16*)(ws + 56950784);
  float* Mtmp  = (float*)(ws + 57229312);
  float* cvec  = (float*)(ws + 57360384);

  float* Z  = (float*)d_out;
  float* yt = Z + (size_t)B_ROWS * 256;

  hipLaunchKernelGGL(prep_weights1, dim3(64), dim3(256), 0, stream,
                     gates, W1, Bmat, W2, b2, W1eff, Mtmp, cvec);
  hipLaunchKernelGGL(prep_weights2, dim3(128), dim3(256), 0, stream,
                     Wout, Bmat, Mtmp, cvec, Pext);
  hipLaunchKernelGGL(prep_inputs, dim3(2048), dim3(256), 0, stream,
                     zdyn, zst, ut, dtp, Xbf, Hext);
  hipLaunchKernelGGL(gemm1_ln_gelu, dim3(256, 4), dim3(256), 0, stream,
                     Xbf, W1eff, b1, gamma, beta, Hext);
  hipLaunchKernelGGL(gemm2_z, dim3(256, 2), dim3(256), 0, stream,
                     Hext, Pext, Z);
  hipLaunchKernelGGL(yt_kernel, dim3(512), dim3(256), 0, stream,
                     Z, Cm, Dm, ut, dtp, yt);
}

// Round 2
// 227.839 us; speedup vs baseline: 1.1413x; 1.1413x over previous
//
#include <hip/hip_runtime.h>
#include <hip/hip_bf16.h>

// Problem constants
#define B_ROWS 32768
#define K1 320      // meas_in = 256 + 64
#define N1 512      // 4 branches * 128
#define KH 512      // Hext width (H' only; ut/const tail synthesized in gemm2)
#define K2 544      // 512 (H') + 16 (ut_dt) + 1 (const) + 15 pad
#define NP 384      // Pext rows: 256 (Z) + 25 (yt via folded C) + padding zeros
#define LN_EPS 1e-5f

typedef __bf16 bf16;
using bf16x8 = __attribute__((ext_vector_type(8))) __bf16;
using f32x4  = __attribute__((ext_vector_type(4))) float;

// ---------------- workspace layout (bytes) ----------------
// Hext  [B,512]  bf16 : 33,554,432 @ 0
// W1eff [512,320]bf16 :    327,680 @ 33554432
// Pext  [384,544]bf16 :    417,792 @ 33882112
// Mtmp  [4,64,128]f32 :    131,072 @ 34299904
// cvec  [256]    f32  :      1,024 @ 34430976
// CW    [25,4,64]f32  :     25,600 @ 34432000
// total ~34.5 MB

__device__ __forceinline__ void gld_lds16(const bf16* g, bf16* l) {
  __builtin_amdgcn_global_load_lds((const __attribute__((address_space(1))) void*)g,
                                   (__attribute__((address_space(3))) void*)l,
                                   16, 0, 0);
}

// exact-GELU via A&S 7.1.26 rational erf (|eps| <= 1.5e-7), branch-free
__device__ __forceinline__ float gelu_exact(float x) {
  float s = x * 0.70710678118f;
  float a = fabsf(s);
  float t = __builtin_amdgcn_rcpf(fmaf(0.3275911f, a, 1.0f));
  float p = fmaf(fmaf(fmaf(fmaf(1.061405429f, t, -1.453152027f),
                           t, 1.421413741f), t, -0.284496736f), t, 0.254829592f) * t;
  float e = __expf(-s * s);
  float er = fmaf(-p, e, 1.0f);
  er = copysignf(er, s);
  return 0.5f * x * (1.0f + er);
}

// ---------------- prep 1: W1eff (gate-folded), Mtmp = BmatG*W2, cvec = BmatG*b2,
//                          CW[o,n,r] = sum_d C[o,d]*Wout[n,d,r]
__global__ __launch_bounds__(256) void prep_weights1(
    const float* __restrict__ gates, const float* __restrict__ W1,
    const float* __restrict__ Bmat,  const float* __restrict__ W2,
    const float* __restrict__ b2,    const float* __restrict__ Wout,
    const float* __restrict__ Cm,
    bf16* __restrict__ W1eff, float* __restrict__ Mtmp, float* __restrict__ cvec,
    float* __restrict__ CW)
{
  const int stride = gridDim.x * blockDim.x;
  const int id = blockIdx.x * blockDim.x + threadIdx.x;
  for (int i = id; i < 512 * 320; i += stride) {
    int col = i / 320;            // n*128+h
    int k   = i - col * 320;
    float wv = W1[i];
    if (k < 256) {
      float g = gates[(col >> 7) * 256 + k];
      wv *= 1.f / (1.f + __expf(-g));
    }
    W1eff[i] = (bf16)wv;
  }
  for (int i = id; i < 4 * 64 * 128; i += stride) {
    int n = i >> 13, r = (i >> 7) & 63, h = i & 127;
    float s = 0.f;
    for (int j = 0; j < 64; ++j)
      s += Bmat[(n * 64 + r) * 80 + j] * W2[(n * 64 + j) * 128 + h];
    Mtmp[i] = s;
  }
  for (int i = id; i < 256; i += stride) {
    int n = i >> 6, r = i & 63;
    float s = 0.f;
    for (int j = 0; j < 64; ++j)
      s += Bmat[(n * 64 + r) * 80 + j] * b2[n * 64 + j];
    cvec[i] = s;
  }
  for (int i = id; i < 25 * 256; i += stride) {
    int o = i >> 8, nr = i & 255;           // nr = n*64+r
    float s = 0.f;
    for (int d = 0; d < 256; ++d)
      s += Cm[o * 256 + d] * Wout[((nr >> 6) * 256 + d) * 64 + (nr & 63)];
    CW[i] = s;
  }
}

// ---------------- prep 2: Pext [384,544]
// rows 0..255 (d): [P | Q | czn | 0] ; rows 256..280 (o): [C*P | C*Q + D | C*czn | 0];
// rows 281..383: 0
__global__ __launch_bounds__(256) void prep_weights2(
    const float* __restrict__ Wout, const float* __restrict__ Bmat,
    const float* __restrict__ Mtmp, const float* __restrict__ cvec,
    const float* __restrict__ CW,   const float* __restrict__ Dm,
    bf16* __restrict__ Pext)
{
  const int stride = gridDim.x * blockDim.x;
  const int id = blockIdx.x * blockDim.x + threadIdx.x;
  for (int i = id; i < NP * 544; i += stride) {
    int dd = i / 544;
    int c  = i - dd * 544;
    float s = 0.f;
    if (dd < 281) {
      const bool isC = (dd >= 256);
      const int o = dd - 256;
      if (c < 512) {
        int n = c >> 7, h = c & 127;
        for (int r = 0; r < 64; ++r) {
          float wv = isC ? CW[(o * 4 + n) * 64 + r] : Wout[(n * 256 + dd) * 64 + r];
          s += wv * Mtmp[(n * 64 + r) * 128 + h];
        }
      } else if (c < 528) {
        int u = c - 512;
        for (int n = 0; n < 4; ++n)
          for (int r = 0; r < 64; ++r) {
            float wv = isC ? CW[(o * 4 + n) * 64 + r] : Wout[(n * 256 + dd) * 64 + r];
            s += wv * Bmat[(n * 64 + r) * 80 + 64 + u];
          }
        if (isC) s += Dm[o * 16 + u];
      } else if (c == 528) {
        for (int n = 0; n < 4; ++n)
          for (int r = 0; r < 64; ++r) {
            float wv = isC ? CW[(o * 4 + n) * 64 + r] : Wout[(n * 256 + dd) * 64 + r];
            s += wv * cvec[n * 64 + r];
          }
      }
    }
    Pext[i] = (bf16)s;
  }
}

// ---------------- GEMM1: H' = GELU(LN(X*W1eff^T + b1)) -> Hext[B,512] bf16
// A staged from f32 z_dyn/z_static with in-register cvt; B via global_load_lds.
__global__ __launch_bounds__(256) void gemm1_ln_gelu(
    const float* __restrict__ zdyn, const float* __restrict__ zst,
    const bf16* __restrict__ W,
    const float* __restrict__ b1, const float* __restrict__ gamma,
    const float* __restrict__ beta, bf16* __restrict__ H)
{
  __shared__ __align__(16) bf16 As[128 * 32];
  __shared__ __align__(16) bf16 Bs[128 * 32];
  __shared__ bf16 hs[128 * 130];
  __shared__ float sgam[128], sbet[128], sb1[128];

  const int t = threadIdx.x;
  const int lane = t & 63, w = t >> 6;
  const int rowBase = blockIdx.x * 128;
  const int colBase = blockIdx.y * 128;

  if (t < 128) {
    sgam[t] = gamma[colBase + t];
    sbet[t] = beta[colBase + t];
    sb1[t]  = b1[colBase + t];
  }

  // A slots (manual f32->bf16 staging): slot s -> row=s>>2, phys quad p=s&3,
  // logical quad q = p ^ ((row>>1)&3)
  const int s0 = t, s1 = t + 256;
  const int rA0 = s0 >> 2, pA0 = s0 & 3, qA0 = pA0 ^ ((rA0 >> 1) & 3);
  const int rA1 = s1 >> 2, pA1 = s1 & 3, qA1 = pA1 ^ ((rA1 >> 1) & 3);
  const float* pd0 = zdyn + (size_t)(rowBase + rA0) * 256 + qA0 * 8;
  const float* pd1 = zdyn + (size_t)(rowBase + rA1) * 256 + qA1 * 8;
  const float* ps0 = zst  + (size_t)(rowBase + rA0) * 64  + qA0 * 8;
  const float* ps1 = zst  + (size_t)(rowBase + rA1) * 64  + qA1 * 8;
  bf16* dA0 = As + rA0 * 32 + pA0 * 8;
  bf16* dA1 = As + rA1 * 32 + pA1 * 8;

  // B slots via global_load_lds (same swizzle baked into the source column)
  const bf16* gB0 = W + (size_t)(colBase + rA0) * K1 + qA0 * 8;
  const bf16* gB1 = W + (size_t)(colBase + rA1) * K1 + qA1 * 8;
  bf16* lB0 = Bs + w * 512;
  bf16* lB1 = Bs + 2048 + w * 512;

  f32x4 acc[4][4];
  #pragma unroll
  for (int i = 0; i < 4; ++i)
    #pragma unroll
    for (int j = 0; j < 4; ++j)
      #pragma unroll
      for (int r = 0; r < 4; ++r) acc[i][j][r] = 0.f;

  const int m16 = lane & 15, q = lane >> 4;
  const int wr = (w >> 1) * 64, wc = (w & 1) * 64;

  for (int it = 0; it < 10; ++it) {
    const float* p0 = (it < 8) ? pd0 + it * 32 : ps0 + (it - 8) * 32;
    const float* p1 = (it < 8) ? pd1 + it * 32 : ps1 + (it - 8) * 32;
    float4 a0 = *(const float4*)p0, a1 = *(const float4*)(p0 + 4);
    float4 b0 = *(const float4*)p1, b1v = *(const float4*)(p1 + 4);
    gld_lds16(gB0 + it * 32, lB0);
    gld_lds16(gB1 + it * 32, lB1);
    bf16x8 va, vb;
    va[0]=(bf16)a0.x; va[1]=(bf16)a0.y; va[2]=(bf16)a0.z; va[3]=(bf16)a0.w;
    va[4]=(bf16)a1.x; va[5]=(bf16)a1.y; va[6]=(bf16)a1.z; va[7]=(bf16)a1.w;
    vb[0]=(bf16)b0.x; vb[1]=(bf16)b0.y; vb[2]=(bf16)b0.z; vb[3]=(bf16)b0.w;
    vb[4]=(bf16)b1v.x; vb[5]=(bf16)b1v.y; vb[6]=(bf16)b1v.z; vb[7]=(bf16)b1v.w;
    *(bf16x8*)dA0 = va;
    *(bf16x8*)dA1 = vb;
    asm volatile("s_waitcnt vmcnt(0)" ::: "memory");
    __syncthreads();
    bf16x8 af[4], bfr[4];
    #pragma unroll
    for (int i = 0; i < 4; ++i) {
      int r = wr + i * 16 + m16;
      af[i]  = *(const bf16x8*)&As[r * 32 + ((q ^ ((r >> 1) & 3)) * 8)];
      int c = wc + i * 16 + m16;
      bfr[i] = *(const bf16x8*)&Bs[c * 32 + ((q ^ ((c >> 1) & 3)) * 8)];
    }
    #pragma unroll
    for (int i = 0; i < 4; ++i)
      #pragma unroll
      for (int j = 0; j < 4; ++j)
        acc[i][j] = __builtin_amdgcn_mfma_f32_16x16x32_bf16(af[i], bfr[j], acc[i][j], 0, 0, 0);
    __syncthreads();
  }

  // epilogue: +b1 -> hs(bf16), vectorized LN stats, LN+GELU, bf16x8 stores
  #pragma unroll
  for (int j = 0; j < 4; ++j) {
    int col = wc + j * 16 + m16;
    float bb = sb1[col];
    #pragma unroll
    for (int i = 0; i < 4; ++i) {
      #pragma unroll
      for (int r = 0; r < 4; ++r) {
        int row = wr + i * 16 + q * 4 + r;
        hs[row * 130 + col] = (bf16)(acc[i][j][r] + bb);
      }
    }
  }
  __syncthreads();

  float* red  = (float*)As;        // As/Bs dead after K-loop
  float* red2 = (float*)Bs;
  float* smu_ = (float*)As + 512;
  float* srs_ = (float*)As + 768;
  {
    int row = t >> 1, c0 = (t & 1) * 64;
    float s = 0.f, s2 = 0.f;
    #pragma unroll
    for (int k = 0; k < 8; ++k) {
      bf16x8 hv = *(const bf16x8*)&hs[row * 130 + c0 + k * 8];
      #pragma unroll
      for (int j = 0; j < 8; ++j) { float v = (float)hv[j]; s += v; s2 = fmaf(v, v, s2); }
    }
    red[t] = s; red2[t] = s2;
  }
  __syncthreads();
  if (t < 128) {
    float ss = red[t * 2] + red[t * 2 + 1];
    float qq = red2[t * 2] + red2[t * 2 + 1];
    float mu = ss * 0.0078125f;
    float var = qq * 0.0078125f - mu * mu;
    smu_[t] = mu;
    srs_[t] = rsqrtf(fmaxf(var, 0.f) + LN_EPS);
  }
  __syncthreads();
  for (int e = t; e < 2048; e += 256) {
    int row = e >> 4, c8 = (e & 15) << 3;
    bf16x8 hv = *(const bf16x8*)&hs[row * 130 + c8];
    float mu = smu_[row], rs = srs_[row];
    bf16x8 ov;
    #pragma unroll
    for (int k = 0; k < 8; ++k) {
      float v = ((float)hv[k] - mu) * rs;
      v = fmaf(v, sgam[c8 + k], sbet[c8 + k]);
      ov[k] = (bf16)gelu_exact(v);
    }
    *(bf16x8*)&H[(size_t)(rowBase + row) * KH + colBase + c8] = ov;
  }
}

// ---------------- GEMM2: [Z | yt] = [Hext | ut_dt | 1] * Pext^T
// K tail (cols 512..543) synthesized from ut in-staging; N rows 256..280 are yt.
__global__ __launch_bounds__(256) void gemm2_z(
    const bf16* __restrict__ A, const bf16* __restrict__ Bm,
    const float* __restrict__ ut, const float* __restrict__ dtp,
    float* __restrict__ Z, float* __restrict__ yt)
{
  __shared__ __align__(16) bf16 As[128 * 32];
  __shared__ __align__(16) bf16 Bs[128 * 32];

  const int t = threadIdx.x;
  const int lane = t & 63, w = t >> 6;
  const int rowBase = blockIdx.x * 128;
  const int colBase = blockIdx.y * 128;
  const float dtv = dtp[0];

  const int s0 = t, s1 = t + 256;
  const int rA0 = s0 >> 2, pA0 = s0 & 3, qA0 = pA0 ^ ((rA0 >> 1) & 3);
  const int rA1 = s1 >> 2, pA1 = s1 & 3, qA1 = pA1 ^ ((rA1 >> 1) & 3);
  const bf16* gA0 = A + (size_t)(rowBase + rA0) * KH + qA0 * 8;
  const bf16* gA1 = A + (size_t)(rowBase + rA1) * KH + qA1 * 8;
  const bf16* gB0 = Bm + (size_t)(colBase + rA0) * K2 + qA0 * 8;
  const bf16* gB1 = Bm + (size_t)(colBase + rA1) * K2 + qA1 * 8;
  bf16* lA0 = As + w * 512;
  bf16* lA1 = As + 2048 + w * 512;
  bf16* lB0 = Bs + w * 512;
  bf16* lB1 = Bs + 2048 + w * 512;

  f32x4 acc[4][4];
  #pragma unroll
  for (int i = 0; i < 4; ++i)
    #pragma unroll
    for (int j = 0; j < 4; ++j)
      #pragma unroll
      for (int r = 0; r < 4; ++r) acc[i][j][r] = 0.f;

  const int m16 = lane & 15, q = lane >> 4;
  const int wr = (w >> 1) * 64, wc = (w & 1) * 64;

  for (int it = 0; it < 17; ++it) {
    if (it < 16) {
      gld_lds16(gA0 + it * 32, lA0);
      gld_lds16(gA1 + it * 32, lA1);
    } else {
      // synthesize logical cols 512..543: [ut*dt (16) | 1 | 0...]
      bf16x8 v0, v1;
      if (qA0 < 2) {
        const float* up = ut + (size_t)(rowBase + rA0) * 16 + qA0 * 8;
        float4 u0 = *(const float4*)up, u1 = *(const float4*)(up + 4);
        v0[0]=(bf16)(u0.x*dtv); v0[1]=(bf16)(u0.y*dtv); v0[2]=(bf16)(u0.z*dtv); v0[3]=(bf16)(u0.w*dtv);
        v0[4]=(bf16)(u1.x*dtv); v0[5]=(bf16)(u1.y*dtv); v0[6]=(bf16)(u1.z*dtv); v0[7]=(bf16)(u1.w*dtv);
      } else {
        #pragma unroll
        for (int k = 0; k < 8; ++k) v0[k] = (bf16)0.f;
        if (qA0 == 2) v0[0] = (bf16)1.f;
      }
      if (qA1 < 2) {
        const float* up = ut + (size_t)(rowBase + rA1) * 16 + qA1 * 8;
        float4 u0 = *(const float4*)up, u1 = *(const float4*)(up + 4);
        v1[0]=(bf16)(u0.x*dtv); v1[1]=(bf16)(u0.y*dtv); v1[2]=(bf16)(u0.z*dtv); v1[3]=(bf16)(u0.w*dtv);
        v1[4]=(bf16)(u1.x*dtv); v1[5]=(bf16)(u1.y*dtv); v1[6]=(bf16)(u1.z*dtv); v1[7]=(bf16)(u1.w*dtv);
      } else {
        #pragma unroll
        for (int k = 0; k < 8; ++k) v1[k] = (bf16)0.f;
        if (qA1 == 2) v1[0] = (bf16)1.f;
      }
      *(bf16x8*)&As[rA0 * 32 + pA0 * 8] = v0;
      *(bf16x8*)&As[rA1 * 32 + pA1 * 8] = v1;
    }
    gld_lds16(gB0 + it * 32, lB0);
    gld_lds16(gB1 + it * 32, lB1);
    asm volatile("s_waitcnt vmcnt(0)" ::: "memory");
    __syncthreads();
    bf16x8 af[4], bfr[4];
    #pragma unroll
    for (int i = 0; i < 4; ++i) {
      int r = wr + i * 16 + m16;
      af[i]  = *(const bf16x8*)&As[r * 32 + ((q ^ ((r >> 1) & 3)) * 8)];
      int c = wc + i * 16 + m16;
      bfr[i] = *(const bf16x8*)&Bs[c * 32 + ((q ^ ((c >> 1) & 3)) * 8)];
    }
    #pragma unroll
    for (int i = 0; i < 4; ++i)
      #pragma unroll
      for (int j = 0; j < 4; ++j)
        acc[i][j] = __builtin_amdgcn_mfma_f32_16x16x32_bf16(af[i], bfr[j], acc[i][j], 0, 0, 0);
    __syncthreads();
  }

  if (colBase < 256) {
    #pragma unroll
    for (int i = 0; i < 4; ++i)
      #pragma unroll
      for (int j = 0; j < 4; ++j) {
        int col = colBase + wc + j * 16 + m16;
        #pragma unroll
        for (int r = 0; r < 4; ++r) {
          int row = rowBase + wr + i * 16 + q * 4 + r;
          Z[(size_t)row * 256 + col] = acc[i][j][r];
        }
      }
  } else {
    #pragma unroll
    for (int i = 0; i < 4; ++i)
      #pragma unroll
      for (int j = 0; j < 4; ++j) {
        int col = colBase + wc + j * 16 + m16;
        if (col < 281) {
          #pragma unroll
          for (int r = 0; r < 4; ++r) {
            int row = rowBase + wr + i * 16 + q * 4 + r;
            yt[(size_t)row * 25 + (col - 256)] = acc[i][j][r];
          }
        }
      }
  }
}

extern "C" void kernel_launch(void* const* d_in, const int* in_sizes, int n_in,
                              void* d_out, int out_size, void* d_ws, size_t ws_size,
                              hipStream_t stream) {
  const float* zdyn  = (const float*)d_in[0];
  const float* zst   = (const float*)d_in[1];
  const float* dtp   = (const float*)d_in[2];
  const float* ut    = (const float*)d_in[3];
  const float* gates = (const float*)d_in[4];
  const float* W1    = (const float*)d_in[5];
  const float* b1    = (const float*)d_in[6];
  const float* gamma = (const float*)d_in[7];
  const float* beta  = (const float*)d_in[8];
  const float* W2    = (const float*)d_in[9];
  const float* b2    = (const float*)d_in[10];
  // d_in[11], d_in[12] (lam_real/lam_imag) dead: h0 = 0
  const float* Bmat  = (const float*)d_in[13];
  const float* Wout  = (const float*)d_in[14];
  const float* Cm    = (const float*)d_in[15];
  const float* Dm    = (const float*)d_in[16];

  char* ws = (char*)d_ws;
  bf16*  Hext  = (bf16*)(ws);
  bf16*  W1eff = (bf16*)(ws + 33554432);
  bf16*  Pext  = (bf16*)(ws + 33882112);
  float* Mtmp  = (float*)(ws + 34299904);
  float* cvec  = (float*)(ws + 34430976);
  float* CW    = (float*)(ws + 34432000);

  float* Z  = (float*)d_out;
  float* yt = Z + (size_t)B_ROWS * 256;

  hipLaunchKernelGGL(prep_weights1, dim3(128), dim3(256), 0, stream,
                     gates, W1, Bmat, W2, b2, Wout, Cm, W1eff, Mtmp, cvec, CW);
  hipLaunchKernelGGL(prep_weights2, dim3(256), dim3(256), 0, stream,
                     Wout, Bmat, Mtmp, cvec, CW, Dm, Pext);
  hipLaunchKernelGGL(gemm1_ln_gelu, dim3(256, 4), dim3(256), 0, stream,
                     zdyn, zst, W1eff, b1, gamma, beta, Hext);
  hipLaunchKernelGGL(gemm2_z, dim3(256, 3), dim3(256), 0, stream,
                     Hext, Pext, ut, dtp, Z, yt);
}